// Round 1
// baseline (323.597 us; speedup 1.0000x reference)
//
#include <hip/hip_runtime.h>
#include <math.h>

#define B_TOT 512
#define S_LEN 256
#define D_IN  64
#define HDIM  128

// XOR-butterfly add within 32-lane halves via ds_swizzle (BitMode: xor<<10 | and=0x1F)
template<int M>
__device__ __forceinline__ float xor_sw(float v) {
    return __int_as_float(__builtin_amdgcn_ds_swizzle(__float_as_int(v), (M << 10) | 0x1F));
}

__device__ __forceinline__ float wave_allsum(float v) {
    v += xor_sw<1>(v);
    v += xor_sw<2>(v);
    v += xor_sw<4>(v);
    v += xor_sw<8>(v);
    v += xor_sw<16>(v);
    v += __shfl_xor(v, 32, 64);   // cross the 32-lane halves
    return v;
}

__device__ __forceinline__ float fast_sigmoid(float x) {
    return 1.0f / (1.0f + __expf(-x));
}
__device__ __forceinline__ float fast_tanh(float x) {
    // exact identity; saturates correctly for |x| large
    return 1.0f - 2.0f / (__expf(2.0f * x) + 1.0f);
}

__global__ void __launch_bounds__(64, 1) qlstm_kernel(
    const float* __restrict__ x,    // (B,S,D)
    const float* __restrict__ Win,  // (192,4)
    const float* __restrict__ bin,  // (4)
    const float* __restrict__ Wout, // (4,128)
    const float* __restrict__ bout, // (128)
    const float* __restrict__ wf,   // (1,3,4)
    const float* __restrict__ wi,
    const float* __restrict__ wu,
    const float* __restrict__ wo,
    float* __restrict__ out)        // outs (B,S,128) ++ hT (B,128) ++ cT (B,128)
{
    const int b = blockIdx.x;   // batch element
    const int l = threadIdx.x;  // lane 0..63; owns hidden units l and l+64

    // ---- per-lane constant weights ----
    const float4* W4 = reinterpret_cast<const float4*>(Win); // row r = 4 contiguous floats
    const float4 wh0 = W4[l];        // W_in rows 0..63   (h part, unit l)
    const float4 wh1 = W4[64 + l];   // W_in rows 64..127 (h part, unit 64+l)
    const float4 wx  = W4[128 + l];  // W_in rows 128..191 (x part, feature l)
    const float4 bn  = *reinterpret_cast<const float4*>(bin);

    float Wo0[4], Wo1[4];
#pragma unroll
    for (int q = 0; q < 4; ++q) {
        Wo0[q] = Wout[q * HDIM + l];
        Wo1[q] = Wout[q * HDIM + 64 + l];
    }
    const float bo0 = bout[l];
    const float bo1 = bout[64 + l];

    // ---- per-(gate,qubit) measurement coefficients u = (-sin b, cos b sin a, cos b cos a)
    // a = RX angle = w[0][q], b(eta) = RY angle = w[1][q]; RZ angle drops out.
    float U[4][4][3];
    {
        const float* wg[4] = {wf, wi, wu, wo};
#pragma unroll
        for (int g = 0; g < 4; ++g) {
#pragma unroll
            for (int q = 0; q < 4; ++q) {
                float a  = wg[g][q];
                float be = wg[g][4 + q];
                float sa = sinf(a),  ca = cosf(a);
                float sb = sinf(be), cb = cosf(be);
                U[g][q][0] = -sb;
                U[g][q][1] = cb * sa;
                U[g][q][2] = cb * ca;
            }
        }
    }

    // ---- recurrent state ----
    float h0 = 0.f, h1 = 0.f, c0 = 0.f, c1 = 0.f;

    const float* xb = x + (size_t)b * (S_LEN * D_IN) + l;
    float* ob = out + (size_t)b * (S_LEN * HDIM) + l;

    // x prefetch, 2 steps deep
    float xa  = xb[0];
    float xnb = xb[D_IN];

    for (int t = 0; t < S_LEN; ++t) {
        const int tl = (t + 2 < S_LEN) ? (t + 2) : (S_LEN - 1);
        float xnew = xb[(size_t)tl * D_IN];   // prefetch for t+2

        // y_j = sum_k h_k Win[k][j] + sum_d x_d Win[128+d][j] + b_in[j]
        float p0 = fmaf(h0, wh0.x, fmaf(h1, wh1.x, xa * wx.x));
        float p1 = fmaf(h0, wh0.y, fmaf(h1, wh1.y, xa * wx.y));
        float p2 = fmaf(h0, wh0.z, fmaf(h1, wh1.z, xa * wx.z));
        float p3 = fmaf(h0, wh0.w, fmaf(h1, wh1.w, xa * wx.w));
        float y0 = wave_allsum(p0) + bn.x;
        float y1 = wave_allsum(p1) + bn.y;
        float y2 = wave_allsum(p2) + bn.z;
        float y3 = wave_allsum(p3) + bn.w;

        // Bloch vectors of encoded qubits (arctan's cancel analytically)
        float nx[4], ny[4], nz[4];
        float ys[4] = {y0, y1, y2, y3};
#pragma unroll
        for (int q = 0; q < 4; ++q) {
            float y  = ys[q];
            float y2s = y * y;
            float r1 = rsqrtf(fmaf(y, y, 1.0f));
            float y4 = y2s * y2s;
            float r2 = rsqrtf(1.0f + y4);
            float xx = r1 * r2;
            nx[q] = xx;
            ny[q] = y2s * xx;
            nz[q] = -y * r1;
        }

        // Pauli-string products (CNOT-ring conjugation, derived analytically):
        // S(X0)=X0X1  S(Y0)=X0Y1Z2Z3      S(Z0)=Z1Z2Z3
        // S(X1)=X1X2  S(Y1)=Z0Y1X2       S(Z1)=Z0Z1
        // S(X2)=X2X3  S(Y2)=Z0Z1Y2X3     S(Z2)=Z0Z1Z2
        // S(X3)=X0X1X3 S(Y3)=-Y0Y1Z2Y3   S(Z3)=Z0Z1Z2Z3
        float nz01 = nz[0] * nz[1];
        float nz23 = nz[2] * nz[3];
        float TX[4], TY[4], TZ[4];
        TX[0] = nx[0] * nx[1];
        TX[1] = nx[1] * nx[2];
        TX[2] = nx[2] * nx[3];
        TX[3] = TX[0] * nx[3];
        TZ[0] = nz[1] * nz23;
        TZ[1] = nz01;
        TZ[2] = nz01 * nz[2];
        TZ[3] = nz01 * nz23;
        TY[0] = (nx[0] * ny[1]) * nz23;
        TY[1] = (nz[0] * ny[1]) * nx[2];
        TY[2] = (nz01 * ny[2]) * nx[3];
        TY[3] = -(ny[0] * ny[1]) * (nz[2] * ny[3]);

        // z_{g,q} = u.(TX,TY,TZ); gate preacts = z @ Wout + bout
        float pre0[4], pre1[4];
#pragma unroll
        for (int g = 0; g < 4; ++g) {
            float s0 = bo0, s1 = bo1;
#pragma unroll
            for (int q = 0; q < 4; ++q) {
                float z = fmaf(U[g][q][0], TX[q],
                          fmaf(U[g][q][1], TY[q],
                               U[g][q][2] * TZ[q]));
                s0 = fmaf(z, Wo0[q], s0);
                s1 = fmaf(z, Wo1[q], s1);
            }
            pre0[g] = s0; pre1[g] = s1;
        }

        // LSTM cell: f=g0, i=g1, g=g2(tanh), o=g3
        float f0 = fast_sigmoid(pre0[0]), f1 = fast_sigmoid(pre1[0]);
        float i0 = fast_sigmoid(pre0[1]), i1 = fast_sigmoid(pre1[1]);
        float g0 = fast_tanh(pre0[2]),    g1 = fast_tanh(pre1[2]);
        float o0 = fast_sigmoid(pre0[3]), o1 = fast_sigmoid(pre1[3]);
        c0 = fmaf(f0, c0, i0 * g0);
        c1 = fmaf(f1, c1, i1 * g1);
        h0 = o0 * fast_tanh(c0);
        h1 = o1 * fast_tanh(c1);

        ob[(size_t)t * HDIM]      = h0;
        ob[(size_t)t * HDIM + 64] = h1;

        xa = xnb; xnb = xnew;
    }

    // final h, c
    float* hT = out + (size_t)B_TOT * S_LEN * HDIM;
    float* cT = hT + (size_t)B_TOT * HDIM;
    hT[(size_t)b * HDIM + l]      = h0;
    hT[(size_t)b * HDIM + 64 + l] = h1;
    cT[(size_t)b * HDIM + l]      = c0;
    cT[(size_t)b * HDIM + 64 + l] = c1;
}

extern "C" void kernel_launch(void* const* d_in, const int* in_sizes, int n_in,
                              void* d_out, int out_size, void* d_ws, size_t ws_size,
                              hipStream_t stream) {
    qlstm_kernel<<<dim3(B_TOT), dim3(64), 0, stream>>>(
        (const float*)d_in[0],  // x
        (const float*)d_in[1],  // W_in
        (const float*)d_in[2],  // b_in
        (const float*)d_in[3],  // W_out
        (const float*)d_in[4],  // b_out
        (const float*)d_in[5],  // w_f
        (const float*)d_in[6],  // w_i
        (const float*)d_in[7],  // w_u
        (const float*)d_in[8],  // w_o
        (float*)d_out);
}

// Round 2
// 242.030 us; speedup vs baseline: 1.3370x; 1.3370x over previous
//
#include <hip/hip_runtime.h>
#include <math.h>

#define B_TOT 512
#define S_LEN 256
#define D_IN  64
#define HDIM  128

// ---- fast scalar ops (raw HW instructions; ~1-2 ulp, threshold is 1.5e-2) ----
__device__ __forceinline__ float rcp_f(float x) { return __builtin_amdgcn_rcpf(x); }
__device__ __forceinline__ float rsq_f(float x) { return __builtin_amdgcn_rsqf(x); }
__device__ __forceinline__ float sig_f(float x) { return rcp_f(1.0f + __expf(-x)); }
__device__ __forceinline__ float tanh_f(float x) { return 1.0f - 2.0f * rcp_f(1.0f + __expf(2.0f * x)); }

// ---- DPP butterfly add (VALU pipe, ~5 cyc dependent vs ~130 for LDS pipe) ----
template<int CTRL>
__device__ __forceinline__ float dpp_add(float v) {
    int t = __builtin_amdgcn_update_dpp(0, __float_as_int(v), CTRL, 0xF, 0xF, true);
    return v + __int_as_float(t);
}

// 64-lane all-reduce sum:
//  4 DPP stages  -> every lane holds its 16-lane row sum
//  3 parallel LDS fetches (xor16 via swizzle, xor32/xor48 via bpermute)
//  -> ONE LDS round-trip instead of two sequential stages.
__device__ __forceinline__ float allsum64(float v, int a32, int a48) {
    v = dpp_add<0xB1>(v);    // quad_perm [1,0,3,2]  : xor 1
    v = dpp_add<0x4E>(v);    // quad_perm [2,3,0,1]  : xor 2
    v = dpp_add<0x141>(v);   // row_half_mirror      : xor 4 (quads already uniform)
    v = dpp_add<0x140>(v);   // row_mirror           : xor 8 (8-groups already uniform)
    float t16 = __int_as_float(__builtin_amdgcn_ds_swizzle(__float_as_int(v), 0x401F)); // l^16
    float t32 = __int_as_float(__builtin_amdgcn_ds_bpermute(a32, __float_as_int(v)));   // l^32
    float t48 = __int_as_float(__builtin_amdgcn_ds_bpermute(a48, __float_as_int(v)));   // l^48
    return (v + t16) + (t32 + t48);
}

__global__ void __launch_bounds__(64, 1) qlstm_kernel(
    const float* __restrict__ x,    // (B,S,D)
    const float* __restrict__ Win,  // (192,4)
    const float* __restrict__ bin,  // (4)
    const float* __restrict__ Wout, // (4,128)
    const float* __restrict__ bout, // (128)
    const float* __restrict__ wf,   // (1,3,4)
    const float* __restrict__ wi,
    const float* __restrict__ wu,
    const float* __restrict__ wo,
    float* __restrict__ out)        // outs (B,S,128) ++ hT (B,128) ++ cT (B,128)
{
    const int b = blockIdx.x;   // batch element
    const int l = threadIdx.x;  // lane 0..63; owns hidden units l and l+64

    // loop-invariant bpermute byte-addresses for the cross-row fetches
    const int a32 = ((l ^ 32) & 63) << 2;
    const int a48 = ((l ^ 48) & 63) << 2;

    // ---- per-lane constant weights ----
    const float4* W4 = reinterpret_cast<const float4*>(Win); // row r = 4 contiguous floats
    const float4 wh0 = W4[l];        // W_in rows 0..63   (h part, unit l)
    const float4 wh1 = W4[64 + l];   // W_in rows 64..127 (h part, unit 64+l)
    const float4 wx  = W4[128 + l];  // W_in rows 128..191 (x part, feature l)
    const float4 bn  = *reinterpret_cast<const float4*>(bin);

    float Wo0[4], Wo1[4];
#pragma unroll
    for (int q = 0; q < 4; ++q) {
        Wo0[q] = Wout[q * HDIM + l];
        Wo1[q] = Wout[q * HDIM + 64 + l];
    }
    const float bo0 = bout[l];
    const float bo1 = bout[64 + l];

    // ---- per-(gate,qubit) measurement coefficients u = (-sin b, cos b sin a, cos b cos a)
    float U[4][4][3];
    {
        const float* wg[4] = {wf, wi, wu, wo};
#pragma unroll
        for (int g = 0; g < 4; ++g) {
#pragma unroll
            for (int q = 0; q < 4; ++q) {
                float a  = wg[g][q];
                float be = wg[g][4 + q];
                float sa = sinf(a),  ca = cosf(a);
                float sb = sinf(be), cb = cosf(be);
                U[g][q][0] = -sb;
                U[g][q][1] = cb * sa;
                U[g][q][2] = cb * ca;
            }
        }
    }

    // ---- recurrent state ----
    float h0 = 0.f, h1 = 0.f, c0 = 0.f, c1 = 0.f;

    const float* xb = x + (size_t)b * (S_LEN * D_IN) + l;
    float* ob = out + (size_t)b * (S_LEN * HDIM) + l;

    // x prefetch, 2 steps deep
    float xa  = xb[0];
    float xnb = xb[D_IN];

    for (int t = 0; t < S_LEN; ++t) {
        const int tl = (t + 2 < S_LEN) ? (t + 2) : (S_LEN - 1);
        float xnew = xb[(size_t)tl * D_IN];   // prefetch for t+2

        // y_j = sum_k h_k Win[k][j] + sum_d x_d Win[128+d][j] + b_in[j]
        float p0 = fmaf(h0, wh0.x, fmaf(h1, wh1.x, xa * wx.x));
        float p1 = fmaf(h0, wh0.y, fmaf(h1, wh1.y, xa * wx.y));
        float p2 = fmaf(h0, wh0.z, fmaf(h1, wh1.z, xa * wx.z));
        float p3 = fmaf(h0, wh0.w, fmaf(h1, wh1.w, xa * wx.w));
        float y0 = allsum64(p0, a32, a48) + bn.x;
        float y1 = allsum64(p1, a32, a48) + bn.y;
        float y2 = allsum64(p2, a32, a48) + bn.z;
        float y3 = allsum64(p3, a32, a48) + bn.w;

        // Bloch vectors of encoded qubits (arctan's cancel analytically)
        float nx[4], ny[4], nz[4];
        float ys[4] = {y0, y1, y2, y3};
#pragma unroll
        for (int q = 0; q < 4; ++q) {
            float y   = ys[q];
            float y2s = y * y;
            float r1  = rsq_f(fmaf(y, y, 1.0f));
            float r2  = rsq_f(fmaf(y2s, y2s, 1.0f));
            float xx  = r1 * r2;
            nx[q] = xx;
            ny[q] = y2s * xx;
            nz[q] = -y * r1;
        }

        // Pauli-string products (CNOT-ring conjugation):
        // S(X0)=X0X1  S(Y0)=X0Y1Z2Z3   S(Z0)=Z1Z2Z3
        // S(X1)=X1X2  S(Y1)=Z0Y1X2    S(Z1)=Z0Z1
        // S(X2)=X2X3  S(Y2)=Z0Z1Y2X3  S(Z2)=Z0Z1Z2
        // S(X3)=X0X1X3 S(Y3)=-Y0Y1Z2Y3 S(Z3)=Z0Z1Z2Z3
        float nz01 = nz[0] * nz[1];
        float nz23 = nz[2] * nz[3];
        float TX[4], TY[4], TZ[4];
        TX[0] = nx[0] * nx[1];
        TX[1] = nx[1] * nx[2];
        TX[2] = nx[2] * nx[3];
        TX[3] = TX[0] * nx[3];
        TZ[0] = nz[1] * nz23;
        TZ[1] = nz01;
        TZ[2] = nz01 * nz[2];
        TZ[3] = nz01 * nz23;
        TY[0] = (nx[0] * ny[1]) * nz23;
        TY[1] = (nz[0] * ny[1]) * nx[2];
        TY[2] = (nz01 * ny[2]) * nx[3];
        TY[3] = -(ny[0] * ny[1]) * (nz[2] * ny[3]);

        // z_{g,q} = u.(TX,TY,TZ); gate preacts = z @ Wout + bout
        float pre0[4], pre1[4];
#pragma unroll
        for (int g = 0; g < 4; ++g) {
            float s0 = bo0, s1 = bo1;
#pragma unroll
            for (int q = 0; q < 4; ++q) {
                float z = fmaf(U[g][q][0], TX[q],
                          fmaf(U[g][q][1], TY[q],
                               U[g][q][2] * TZ[q]));
                s0 = fmaf(z, Wo0[q], s0);
                s1 = fmaf(z, Wo1[q], s1);
            }
            pre0[g] = s0; pre1[g] = s1;
        }

        // LSTM cell: f=g0, i=g1, g=g2(tanh), o=g3
        float f0 = sig_f(pre0[0]),  f1 = sig_f(pre1[0]);
        float i0 = sig_f(pre0[1]),  i1 = sig_f(pre1[1]);
        float g0 = tanh_f(pre0[2]), g1 = tanh_f(pre1[2]);
        float o0 = sig_f(pre0[3]),  o1 = sig_f(pre1[3]);
        c0 = fmaf(f0, c0, i0 * g0);
        c1 = fmaf(f1, c1, i1 * g1);
        h0 = o0 * tanh_f(c0);
        h1 = o1 * tanh_f(c1);

        ob[(size_t)t * HDIM]      = h0;
        ob[(size_t)t * HDIM + 64] = h1;

        xa = xnb; xnb = xnew;
    }

    // final h, c
    float* hT = out + (size_t)B_TOT * S_LEN * HDIM;
    float* cT = hT + (size_t)B_TOT * HDIM;
    hT[(size_t)b * HDIM + l]      = h0;
    hT[(size_t)b * HDIM + 64 + l] = h1;
    cT[(size_t)b * HDIM + l]      = c0;
    cT[(size_t)b * HDIM + 64 + l] = c1;
}

extern "C" void kernel_launch(void* const* d_in, const int* in_sizes, int n_in,
                              void* d_out, int out_size, void* d_ws, size_t ws_size,
                              hipStream_t stream) {
    qlstm_kernel<<<dim3(B_TOT), dim3(64), 0, stream>>>(
        (const float*)d_in[0],  // x
        (const float*)d_in[1],  // W_in
        (const float*)d_in[2],  // b_in
        (const float*)d_in[3],  // W_out
        (const float*)d_in[4],  // b_out
        (const float*)d_in[5],  // w_f
        (const float*)d_in[6],  // w_i
        (const float*)d_in[7],  // w_u
        (const float*)d_in[8],  // w_o
        (float*)d_out);
}

// Round 4
// 236.993 us; speedup vs baseline: 1.3654x; 1.0213x over previous
//
#include <hip/hip_runtime.h>
#include <math.h>

#define B_TOT 512
#define S_LEN 256
#define D_IN  64
#define HDIM  128

// ---- fast scalar ops (raw HW instructions; ~1-2 ulp, threshold is 1.5e-2) ----
__device__ __forceinline__ float rcp_f(float x) { return __builtin_amdgcn_rcpf(x); }
__device__ __forceinline__ float rsq_f(float x) { return __builtin_amdgcn_rsqf(x); }
__device__ __forceinline__ float sig_f(float x) { return rcp_f(1.0f + __expf(-x)); }
__device__ __forceinline__ float tanh_f(float x) { return 1.0f - 2.0f * rcp_f(1.0f + __expf(2.0f * x)); }

// ---- DPP butterfly add (VALU pipe) ----
template<int CTRL>
__device__ __forceinline__ float dpp_add(float v) {
    int t = __builtin_amdgcn_update_dpp(0, __float_as_int(v), CTRL, 0xF, 0xF, true);
    return v + __int_as_float(t);
}

// 64-lane all-reduce: 4 DPP stages -> row sums, then 4 readlanes (SGPR, no LDS)
// + 3 VALU adds. Zero LDS traffic, zero lgkmcnt waits, documented ops only.
__device__ __forceinline__ float allsum64(float v) {
    v = dpp_add<0xB1>(v);    // quad_perm [1,0,3,2]  : xor 1
    v = dpp_add<0x4E>(v);    // quad_perm [2,3,0,1]  : xor 2
    v = dpp_add<0x141>(v);   // row_half_mirror      : xor 4
    v = dpp_add<0x140>(v);   // row_mirror           : xor 8
    int r0 = __builtin_amdgcn_readlane(__float_as_int(v), 0);
    int r1 = __builtin_amdgcn_readlane(__float_as_int(v), 16);
    int r2 = __builtin_amdgcn_readlane(__float_as_int(v), 32);
    int r3 = __builtin_amdgcn_readlane(__float_as_int(v), 48);
    return (__int_as_float(r0) + __int_as_float(r1))
         + (__int_as_float(r2) + __int_as_float(r3));
}

__global__ void __launch_bounds__(64, 1) qlstm_kernel(
    const float* __restrict__ x,    // (B,S,D)
    const float* __restrict__ Win,  // (192,4)
    const float* __restrict__ bin,  // (4)
    const float* __restrict__ Wout, // (4,128)
    const float* __restrict__ bout, // (128)
    const float* __restrict__ wf,   // (1,3,4)
    const float* __restrict__ wi,
    const float* __restrict__ wu,
    const float* __restrict__ wo,
    float* __restrict__ out)        // outs (B,S,128) ++ hT (B,128) ++ cT (B,128)
{
    const int b = blockIdx.x;   // batch element
    const int l = threadIdx.x;  // lane 0..63; owns hidden units l and l+64

    // ---- per-lane constant weights ----
    const float4* W4 = reinterpret_cast<const float4*>(Win); // row r = 4 contiguous floats
    const float4 wh0 = W4[l];        // W_in rows 0..63   (h part, unit l)
    const float4 wh1 = W4[64 + l];   // W_in rows 64..127 (h part, unit 64+l)
    const float4 wx  = W4[128 + l];  // W_in rows 128..191 (x part, feature l)
    const float4 bn  = *reinterpret_cast<const float4*>(bin);

    float Wo0[4], Wo1[4];
#pragma unroll
    for (int q = 0; q < 4; ++q) {
        Wo0[q] = Wout[q * HDIM + l];
        Wo1[q] = Wout[q * HDIM + 64 + l];
    }
    const float bo0 = bout[l];
    const float bo1 = bout[64 + l];

    // ---- per-(gate,qubit) measurement coefficients u = (-sin b, cos b sin a, cos b cos a)
    float U[4][4][3];
    {
        const float* wg[4] = {wf, wi, wu, wo};
#pragma unroll
        for (int g = 0; g < 4; ++g) {
#pragma unroll
            for (int q = 0; q < 4; ++q) {
                float a  = wg[g][q];
                float be = wg[g][4 + q];
                float sa = sinf(a),  ca = cosf(a);
                float sb = sinf(be), cb = cosf(be);
                U[g][q][0] = -sb;
                U[g][q][1] = cb * sa;
                U[g][q][2] = cb * ca;
            }
        }
    }

    // ---- recurrent state ----
    float h0 = 0.f, h1 = 0.f, c0 = 0.f, c1 = 0.f;

    const float* xb = x + (size_t)b * (S_LEN * D_IN) + l;
    float* ob = out + (size_t)b * (S_LEN * HDIM) + l;

    // x prefetch, 2 steps deep; x-part of the input projection is precomputed
    // off the critical path (it doesn't depend on h).
    float xa  = xb[0];
    float xnb = xb[D_IN];
    float xc0 = xa * wx.x, xc1 = xa * wx.y, xc2 = xa * wx.z, xc3 = xa * wx.w;

    for (int t = 0; t < S_LEN; ++t) {
        const int tl = (t + 2 < S_LEN) ? (t + 2) : (S_LEN - 1);
        float xnew = xb[(size_t)tl * D_IN];   // prefetch for t+2

        // y_j = sum_k h_k Win[k][j] + (precomputed x part) + b_in[j]
        float p0 = fmaf(h0, wh0.x, fmaf(h1, wh1.x, xc0));
        float p1 = fmaf(h0, wh0.y, fmaf(h1, wh1.y, xc1));
        float p2 = fmaf(h0, wh0.z, fmaf(h1, wh1.z, xc2));
        float p3 = fmaf(h0, wh0.w, fmaf(h1, wh1.w, xc3));
        float y0 = allsum64(p0) + bn.x;
        float y1 = allsum64(p1) + bn.y;
        float y2 = allsum64(p2) + bn.z;
        float y3 = allsum64(p3) + bn.w;

        // x-part for NEXT step (off critical path)
        xc0 = xnb * wx.x; xc1 = xnb * wx.y; xc2 = xnb * wx.z; xc3 = xnb * wx.w;

        // Bloch vectors of encoded qubits (arctan's cancel analytically)
        float nx[4], ny[4], nz[4];
        float ys[4] = {y0, y1, y2, y3};
#pragma unroll
        for (int q = 0; q < 4; ++q) {
            float y   = ys[q];
            float y2s = y * y;
            float r1  = rsq_f(fmaf(y, y, 1.0f));
            float r2  = rsq_f(fmaf(y2s, y2s, 1.0f));
            float xx  = r1 * r2;
            nx[q] = xx;
            ny[q] = y2s * xx;
            nz[q] = -y * r1;
        }

        // Pauli-string products (CNOT-ring conjugation):
        // S(X0)=X0X1  S(Y0)=X0Y1Z2Z3   S(Z0)=Z1Z2Z3
        // S(X1)=X1X2  S(Y1)=Z0Y1X2    S(Z1)=Z0Z1
        // S(X2)=X2X3  S(Y2)=Z0Z1Y2X3  S(Z2)=Z0Z1Z2
        // S(X3)=X0X1X3 S(Y3)=-Y0Y1Z2Y3 S(Z3)=Z0Z1Z2Z3
        float nz01 = nz[0] * nz[1];
        float nz23 = nz[2] * nz[3];
        float TX[4], TY[4], TZ[4];
        TX[0] = nx[0] * nx[1];
        TX[1] = nx[1] * nx[2];
        TX[2] = nx[2] * nx[3];
        TX[3] = TX[0] * nx[3];
        TZ[0] = nz[1] * nz23;
        TZ[1] = nz01;
        TZ[2] = nz01 * nz[2];
        TZ[3] = nz01 * nz23;
        TY[0] = (nx[0] * ny[1]) * nz23;
        TY[1] = (nz[0] * ny[1]) * nx[2];
        TY[2] = (nz01 * ny[2]) * nx[3];
        TY[3] = -(ny[0] * ny[1]) * (nz[2] * ny[3]);

        // z_{g,q} = u.(TX,TY,TZ); gate preacts = z @ Wout + bout
        float pre0[4], pre1[4];
#pragma unroll
        for (int g = 0; g < 4; ++g) {
            float s0 = bo0, s1 = bo1;
#pragma unroll
            for (int q = 0; q < 4; ++q) {
                float z = fmaf(U[g][q][0], TX[q],
                          fmaf(U[g][q][1], TY[q],
                               U[g][q][2] * TZ[q]));
                s0 = fmaf(z, Wo0[q], s0);
                s1 = fmaf(z, Wo1[q], s1);
            }
            pre0[g] = s0; pre1[g] = s1;
        }

        // LSTM cell: f=g0, i=g1, g=g2(tanh), o=g3
        float f0 = sig_f(pre0[0]),  f1 = sig_f(pre1[0]);
        float i0 = sig_f(pre0[1]),  i1 = sig_f(pre1[1]);
        float g0 = tanh_f(pre0[2]), g1 = tanh_f(pre1[2]);
        float o0 = sig_f(pre0[3]),  o1 = sig_f(pre1[3]);
        c0 = fmaf(f0, c0, i0 * g0);
        c1 = fmaf(f1, c1, i1 * g1);
        h0 = o0 * tanh_f(c0);
        h1 = o1 * tanh_f(c1);

        ob[(size_t)t * HDIM]      = h0;
        ob[(size_t)t * HDIM + 64] = h1;

        xa = xnb; xnb = xnew;
    }

    // final h, c
    float* hT = out + (size_t)B_TOT * S_LEN * HDIM;
    float* cT = hT + (size_t)B_TOT * HDIM;
    hT[(size_t)b * HDIM + l]      = h0;
    hT[(size_t)b * HDIM + 64 + l] = h1;
    cT[(size_t)b * HDIM + l]      = c0;
    cT[(size_t)b * HDIM + 64 + l] = c1;
}

extern "C" void kernel_launch(void* const* d_in, const int* in_sizes, int n_in,
                              void* d_out, int out_size, void* d_ws, size_t ws_size,
                              hipStream_t stream) {
    qlstm_kernel<<<dim3(B_TOT), dim3(64), 0, stream>>>(
        (const float*)d_in[0],  // x
        (const float*)d_in[1],  // W_in
        (const float*)d_in[2],  // b_in
        (const float*)d_in[3],  // W_out
        (const float*)d_in[4],  // b_out
        (const float*)d_in[5],  // w_f
        (const float*)d_in[6],  // w_i
        (const float*)d_in[7],  // w_u
        (const float*)d_in[8],  // w_o
        (float*)d_out);
}

// Round 5
// 229.691 us; speedup vs baseline: 1.4088x; 1.0318x over previous
//
#include <hip/hip_runtime.h>
#include <math.h>

#define B_TOT 512
#define S_LEN 256
#define D_IN  64
#define HDIM  128

// ---- fast scalar ops (raw HW instructions; ~1-2 ulp, threshold is 1.5e-2) ----
__device__ __forceinline__ float rcp_f(float x) { return __builtin_amdgcn_rcpf(x); }
__device__ __forceinline__ float rsq_f(float x) { return __builtin_amdgcn_rsqf(x); }
__device__ __forceinline__ float sig_f(float x) { return rcp_f(1.0f + __expf(-x)); }
__device__ __forceinline__ float tanh_f(float x) { return 1.0f - 2.0f * rcp_f(1.0f + __expf(2.0f * x)); }

// ---- DPP butterfly add (VALU pipe) ----
template<int CTRL>
__device__ __forceinline__ float dpp_add(float v) {
    int t = __builtin_amdgcn_update_dpp(0, __float_as_int(v), CTRL, 0xF, 0xF, true);
    return v + __int_as_float(t);
}

// 64-lane all-reduce: 4 DPP stages -> 16-lane row sums, then 4 readlanes + 3 adds.
__device__ __forceinline__ float allsum64(float v) {
    v = dpp_add<0xB1>(v);    // xor 1
    v = dpp_add<0x4E>(v);    // xor 2
    v = dpp_add<0x141>(v);   // xor 4 (row_half_mirror)
    v = dpp_add<0x140>(v);   // xor 8 (row_mirror)
    int r0 = __builtin_amdgcn_readlane(__float_as_int(v), 0);
    int r1 = __builtin_amdgcn_readlane(__float_as_int(v), 16);
    int r2 = __builtin_amdgcn_readlane(__float_as_int(v), 32);
    int r3 = __builtin_amdgcn_readlane(__float_as_int(v), 48);
    return (__int_as_float(r0) + __int_as_float(r1))
         + (__int_as_float(r2) + __int_as_float(r3));
}

__global__ void __launch_bounds__(64, 1) qlstm_kernel(
    const float* __restrict__ x,    // (B,S,D)
    const float* __restrict__ Win,  // (192,4)
    const float* __restrict__ bin,  // (4)
    const float* __restrict__ Wout, // (4,128)
    const float* __restrict__ bout, // (128)
    const float* __restrict__ wf,   // (1,3,4)
    const float* __restrict__ wi,
    const float* __restrict__ wu,
    const float* __restrict__ wo,
    float* __restrict__ out)        // outs (B,S,128) ++ hT (B,128) ++ cT (B,128)
{
    const int b = blockIdx.x;   // batch element
    const int l = threadIdx.x;  // lane 0..63; owns hidden units l and l+64

    // ---- per-lane constant weights ----
    const float4* W4 = reinterpret_cast<const float4*>(Win);
    const float4 wh0 = W4[l];        // W_in rows 0..63   (h part, unit l)
    const float4 wh1 = W4[64 + l];   // W_in rows 64..127 (h part, unit 64+l)
    const float4 wx  = W4[128 + l];  // W_in rows 128..191 (x part, feature l)
    // b_in folded in pre-reduction: each lane adds b/64, 64-lane sum gives b.
    const float4 bn4 = *reinterpret_cast<const float4*>(bin);
    const float bn0 = bn4.x * 0.015625f, bn1 = bn4.y * 0.015625f,
                bn2 = bn4.z * 0.015625f, bn3 = bn4.w * 0.015625f;

    float Wo0[4], Wo1[4];
#pragma unroll
    for (int q = 0; q < 4; ++q) {
        Wo0[q] = Wout[q * HDIM + l];
        Wo1[q] = Wout[q * HDIM + 64 + l];
    }
    const float bo0 = bout[l];
    const float bo1 = bout[64 + l];

    // ---- per-(gate,qubit) measurement coefficients u = (-sin b, cos b sin a, cos b cos a)
    float U[4][4][3];
    {
        const float* wg[4] = {wf, wi, wu, wo};
#pragma unroll
        for (int g = 0; g < 4; ++g) {
#pragma unroll
            for (int q = 0; q < 4; ++q) {
                float a  = wg[g][q];
                float be = wg[g][4 + q];
                float sa = sinf(a),  ca = cosf(a);
                float sb = sinf(be), cb = cosf(be);
                U[g][q][0] = -sb;
                U[g][q][1] = cb * sa;
                U[g][q][2] = cb * ca;
            }
        }
    }

    // ---- recurrent state ----
    float h0 = 0.f, h1 = 0.f, c0 = 0.f, c1 = 0.f;

    const float* xb = x + (size_t)b * (S_LEN * D_IN) + l;
    float* ob = out + (size_t)b * (S_LEN * HDIM) + l;

    // one full LSTM step; xval is this step's x feature for this lane
    auto step = [&](float xval) {
        float xc0 = fmaf(xval, wx.x, bn0);
        float xc1 = fmaf(xval, wx.y, bn1);
        float xc2 = fmaf(xval, wx.z, bn2);
        float xc3 = fmaf(xval, wx.w, bn3);
        float p0 = fmaf(h0, wh0.x, fmaf(h1, wh1.x, xc0));
        float p1 = fmaf(h0, wh0.y, fmaf(h1, wh1.y, xc1));
        float p2 = fmaf(h0, wh0.z, fmaf(h1, wh1.z, xc2));
        float p3 = fmaf(h0, wh0.w, fmaf(h1, wh1.w, xc3));
        float ys[4];
        ys[0] = allsum64(p0);
        ys[1] = allsum64(p1);
        ys[2] = allsum64(p2);
        ys[3] = allsum64(p3);

        // Bloch vectors (arctan's cancel analytically)
        float nx[4], ny[4], nz[4];
#pragma unroll
        for (int q = 0; q < 4; ++q) {
            float y   = ys[q];
            float y2s = y * y;
            float r1  = rsq_f(fmaf(y, y, 1.0f));
            float r2  = rsq_f(fmaf(y2s, y2s, 1.0f));
            float xx  = r1 * r2;
            nx[q] = xx;
            ny[q] = y2s * xx;
            nz[q] = -y * r1;
        }

        // Pauli-string products (CNOT-ring conjugation)
        float nz01 = nz[0] * nz[1];
        float nz23 = nz[2] * nz[3];
        float TX[4], TY[4], TZ[4];
        TX[0] = nx[0] * nx[1];
        TX[1] = nx[1] * nx[2];
        TX[2] = nx[2] * nx[3];
        TX[3] = TX[0] * nx[3];
        TZ[0] = nz[1] * nz23;
        TZ[1] = nz01;
        TZ[2] = nz01 * nz[2];
        TZ[3] = nz01 * nz23;
        TY[0] = (nx[0] * ny[1]) * nz23;
        TY[1] = (nz[0] * ny[1]) * nx[2];
        TY[2] = (nz01 * ny[2]) * nx[3];
        TY[3] = -(ny[0] * ny[1]) * (nz[2] * ny[3]);

        float pre0[4], pre1[4];
#pragma unroll
        for (int g = 0; g < 4; ++g) {
            float s0 = bo0, s1 = bo1;
#pragma unroll
            for (int q = 0; q < 4; ++q) {
                float z = fmaf(U[g][q][0], TX[q],
                          fmaf(U[g][q][1], TY[q],
                               U[g][q][2] * TZ[q]));
                s0 = fmaf(z, Wo0[q], s0);
                s1 = fmaf(z, Wo1[q], s1);
            }
            pre0[g] = s0; pre1[g] = s1;
        }

        float f0 = sig_f(pre0[0]),  f1 = sig_f(pre1[0]);
        float i0 = sig_f(pre0[1]),  i1 = sig_f(pre1[1]);
        float g0 = tanh_f(pre0[2]), g1 = tanh_f(pre1[2]);
        float o0 = sig_f(pre0[3]),  o1 = sig_f(pre1[3]);
        c0 = fmaf(f0, c0, i0 * g0);
        c1 = fmaf(f1, c1, i1 * g1);
        h0 = o0 * tanh_f(c0);
        h1 = o1 * tanh_f(c1);
    };

    // ---- software-pipelined groups of 4 steps ----
    // pending h's from the previous group are stored one group late (WAR slack
    // ~4 steps), x is register-prefetched one group ahead.
    float xg[4], xn[4];
#pragma unroll
    for (int j = 0; j < 4; ++j) {
        xg[j] = xb[(size_t)j * D_IN];
        xn[j] = xb[(size_t)(4 + j) * D_IN];
    }

    float ph0[4], ph1[4];

    // group 0: compute only
#pragma unroll
    for (int j = 0; j < 4; ++j) {
        step(xg[j]);
        ph0[j] = h0; ph1[j] = h1;
    }

    for (int g = 1; g < S_LEN / 4; ++g) {
        const int tprev = (g - 1) * 4;
        float* op = ob + (size_t)tprev * HDIM;
        // store previous group's outputs (registers distinct from nh)
#pragma unroll
        for (int j = 0; j < 4; ++j) {
            op[(size_t)j * HDIM]      = ph0[j];
            op[(size_t)j * HDIM + 64] = ph1[j];
        }
        // rotate prefetched x, prefetch next group (clamped)
#pragma unroll
        for (int j = 0; j < 4; ++j) xg[j] = xn[j];
#pragma unroll
        for (int j = 0; j < 4; ++j) {
            int tn = (g + 1) * 4 + j;
            if (tn > S_LEN - 1) tn = S_LEN - 1;
            xn[j] = xb[(size_t)tn * D_IN];
        }
        // compute this group
        float nh0[4], nh1[4];
#pragma unroll
        for (int j = 0; j < 4; ++j) {
            step(xg[j]);
            nh0[j] = h0; nh1[j] = h1;
        }
#pragma unroll
        for (int j = 0; j < 4; ++j) { ph0[j] = nh0[j]; ph1[j] = nh1[j]; }
    }

    // epilogue: store last group
    {
        const int tprev = S_LEN - 4;
        float* op = ob + (size_t)tprev * HDIM;
#pragma unroll
        for (int j = 0; j < 4; ++j) {
            op[(size_t)j * HDIM]      = ph0[j];
            op[(size_t)j * HDIM + 64] = ph1[j];
        }
    }

    // final h, c
    float* hT = out + (size_t)B_TOT * S_LEN * HDIM;
    float* cT = hT + (size_t)B_TOT * HDIM;
    hT[(size_t)b * HDIM + l]      = h0;
    hT[(size_t)b * HDIM + 64 + l] = h1;
    cT[(size_t)b * HDIM + l]      = c0;
    cT[(size_t)b * HDIM + 64 + l] = c1;
}

extern "C" void kernel_launch(void* const* d_in, const int* in_sizes, int n_in,
                              void* d_out, int out_size, void* d_ws, size_t ws_size,
                              hipStream_t stream) {
    qlstm_kernel<<<dim3(B_TOT), dim3(64), 0, stream>>>(
        (const float*)d_in[0],  // x
        (const float*)d_in[1],  // W_in
        (const float*)d_in[2],  // b_in
        (const float*)d_in[3],  // W_out
        (const float*)d_in[4],  // b_out
        (const float*)d_in[5],  // w_f
        (const float*)d_in[6],  // w_i
        (const float*)d_in[7],  // w_u
        (const float*)d_in[8],  // w_o
        (float*)d_out);
}